// Round 8
// baseline (390.594 us; speedup 1.0000x reference)
//
#include <hip/hip_runtime.h>

// ---------- problem constants ----------
#define CDIM   768
#define NSEQ   196
#define NVIEW  5
#define BN_TOT 6272       // B*N
#define SLAB   4816896    // BN_TOT*CDIM
#define WSLAB  589824     // CDIM*CDIM

typedef __attribute__((ext_vector_type(8))) short short8;  // 8 bf16 (4 VGPRs)
typedef __attribute__((ext_vector_type(4))) float f32x4;

// ---------- helpers ----------
__device__ __forceinline__ float bf_lo(unsigned u) { return __uint_as_float(u << 16); }
__device__ __forceinline__ float bf_hi(unsigned u) { return __uint_as_float(u & 0xffff0000u); }
__device__ __forceinline__ unsigned short f2bf(float f) {
  unsigned u = __float_as_uint(f);
  return (unsigned short)((u + 0x7fffu + ((u >> 16) & 1u)) >> 16);  // RNE
}
__device__ __forceinline__ unsigned pack2(float f0, float f1) {
  return (unsigned)f2bf(f0) | ((unsigned)f2bf(f1) << 16);
}
__device__ __forceinline__ float ftanh(float x) {
  x = fminf(fmaxf(x, -10.f), 10.f);
  float e = __expf(2.f * x);
  return (e - 1.f) / (e + 1.f);
}
__device__ __forceinline__ void async_cp16(const void* g, void* l) {
  __builtin_amdgcn_global_load_lds((const __attribute__((address_space(1))) unsigned*)g,
                                   (__attribute__((address_space(3))) unsigned*)l, 16, 0, 0);
}

// ---------- launch 1: weight transposes (z<7) + xb/mean pass (z==7) ----------
// z<7: fp32->bf16 transposes of 7 768x768 mats (R0-verified body).
// z==7 (R4-verified structure + xb store): 576 blocks x 11 bn; threads 0..191
// each handle 4 cols: xb[v][bn][c] = bf16(x), cb[bn][c] = bf16(mean_v x).
__global__ __launch_bounds__(256) void k_tr2(const float* __restrict__ wv,
                                             const float* __restrict__ w1,
                                             const float* __restrict__ x,
                                             unsigned short* __restrict__ wvT,
                                             unsigned short* __restrict__ w1aT,
                                             unsigned short* __restrict__ w1bT,
                                             unsigned short* __restrict__ xb,
                                             unsigned short* __restrict__ cb) {
  const int m = blockIdx.z;
  const int tx = threadIdx.x, ty = threadIdx.y, t = ty * 32 + tx;
  if (m == 7) {               // ---- xb + mean works ----
    const int bidx = blockIdx.y * 24 + blockIdx.x;   // 0..575
    if (t < 192) {
      const int col = t * 4;
      for (int i = 0; i < 11; ++i) {
        const int bn = bidx * 11 + i;
        if (bn >= BN_TOT) break;
        const int b = bn / NSEQ, n = bn - b * NSEQ;
        const float* xp = x + ((size_t)(b * NVIEW) * NSEQ + n) * CDIM + col;
        float s0 = 0, s1 = 0, s2 = 0, s3 = 0;
#pragma unroll
        for (int v = 0; v < NVIEW; ++v) {
          float4 p = *(const float4*)(xp + (size_t)v * (NSEQ * CDIM));
          s0 += p.x; s1 += p.y; s2 += p.z; s3 += p.w;
          uint2 q; q.x = pack2(p.x, p.y); q.y = pack2(p.z, p.w);
          *(uint2*)(xb + ((size_t)v * BN_TOT + bn) * CDIM + col) = q;
        }
        uint2 o;
        o.x = pack2(s0 * 0.2f, s1 * 0.2f);
        o.y = pack2(s2 * 0.2f, s3 * 0.2f);
        *(uint2*)(cb + (size_t)bn * CDIM + col) = o;
      }
    }
    return;
  }
  __shared__ float tile[32][33];
  const float* src;
  unsigned short* dst;
  if (m < NVIEW)      { src = wv + (size_t)m * WSLAB; dst = wvT + (size_t)m * WSLAB; }
  else if (m == NVIEW){ src = w1;                     dst = w1aT; }
  else                { src = w1 + WSLAB;             dst = w1bT; }
  const int x0 = blockIdx.x * 32, y0 = blockIdx.y * 32;
#pragma unroll
  for (int i = 0; i < 4; ++i)
    tile[ty + i * 8][tx] = src[(size_t)(y0 + ty + i * 8) * CDIM + x0 + tx];
  __syncthreads();
#pragma unroll
  for (int i = 0; i < 4; ++i)
    dst[(size_t)(x0 + ty + i * 8) * CDIM + y0 + tx] = f2bf(tile[tx][ty + i * 8]);
}

// ---------- 256x128-tile GEMM, 128x64 WAVE tile, 3-ring, counted vmcnt ----------
// Delta vs R7 champion (808 TF, measured LDS-read-BW-bound at ~1583 cy/tile):
// wave tile 64x64 -> 128x64 raises FLOP/LDS-byte 1.33x (12KB ds_read per
// 524 KFLOP). 256 thr, 4 waves 2m x 2n; acc 128 VGPR; launch_bounds(256,2).
// Ring: 3 slots x 24KB (A 16KB + B 8KB) = 72KB dyn LDS -> 2 blocks/CU.
// Per K-tile: stage kt+2 (6 DMA ops) ; ds_read kt ; 32 MFMA ; vmcnt(6) ; bar.
// Never drains until tail (kt=22: vmcnt(0)). Slot (kt+2)%3 consumed at kt-1.
// XOR swizzle (chunk ^= (row>>1)&3): pre-swizzled global source + ds_read
// (both-sides, rule 21); op row-offsets are multiples of 64 -> swizzle-safe.
// M-tail: 6272 = 24*256+128 -> mt=24, wm=128 waves skip stores (uniform);
// their A-reads land in adjacent workspace regions (audited in-bounds).
// MODE 0 (1650 = 11z x 25mt x 6nt): z<5 proj=xb_v@wvT_v ; z in[5,10)
//   xw1=xb_v@w1aT ; z==10 cw1=cb@w1bT.
// MODE 1 (750 = 5z x 25mt x 6nt): pw1b_v = projb_v @ w1bT.
template <int MODE>
__global__ __launch_bounds__(256, 2) void gemm_w(const unsigned short* __restrict__ P0,
                                                 const unsigned short* __restrict__ cbp,
                                                 const unsigned short* __restrict__ wvT,
                                                 const unsigned short* __restrict__ w1aT,
                                                 const unsigned short* __restrict__ w1bT,
                                                 unsigned short* __restrict__ Q0,
                                                 unsigned short* __restrict__ Q1,
                                                 unsigned short* __restrict__ Q2) {
  extern __shared__ unsigned short ldsb[];   // 3 slots x 12288 shorts = 72 KB
  constexpr int NWG = (MODE == 0) ? 1650 : 750;
  // bijective XCD swizzle (m204)
  const int orig = blockIdx.x;
  const int qq = NWG >> 3, rr = NWG & 7, xcd = orig & 7, slot0 = orig >> 3;
  const int wk = (xcd < rr ? xcd * (qq + 1) : rr * (qq + 1) + (xcd - rr) * qq) + slot0;
  const int nt = wk % 6, mt = (wk / 6) % 25, z = wk / 150;

  const int t = threadIdx.x, w = t >> 6, lane = t & 63, lr = lane & 15, lq = lane >> 4;
  const int wm = (w >> 1) * 128;        // 0 / 128
  const int wn = (w & 1) * 64;          // 0 / 64
  const int colBase = nt * 128, mrow0 = mt * 256;

  const unsigned short *A, *Bt;
  unsigned short* C;
  if (MODE == 0) {
    if (z == 10)    { A = cbp; Bt = w1bT; C = Q2; }
    else if (z < 5) { A = P0 + (size_t)z * SLAB;       Bt = wvT + (size_t)z * WSLAB; C = Q0 + (size_t)z * SLAB; }
    else            { A = P0 + (size_t)(z - 5) * SLAB; Bt = w1aT;                    C = Q1 + (size_t)(z - 5) * SLAB; }
  } else {
    A = P0 + (size_t)z * SLAB; Bt = w1bT; C = Q0 + (size_t)z * SLAB;
  }

  // staging sources (pre-swizzled k-chunk; DMA dest linear: rule-21 pair)
  const int swz = ((t & 3) ^ ((t >> 3) & 3)) << 3;
  const unsigned short* gA = A  + (size_t)(mrow0 + (t >> 2)) * CDIM + swz;
  const unsigned short* gB = Bt + (size_t)(colBase + (t >> 2)) * CDIM + swz;
  // ds_read address (same involution: chunk = lq ^ ((lr>>1)&3))
  const int kch = ((lq ^ ((lr >> 1) & 3)) << 3);

  // 6 vmcnt-ops per tile: A 16KB (4 ops x 64 rows), B 8KB (2 ops x 64 rows).
  // Op o dest = slot + o*2048 shorts + wave*512 shorts (+ lane*16B by HW).
#define STAGE(kt, s) {                                                            \
    unsigned short* d_ = ldsb + (s) * 12288 + (w << 9);                           \
    const unsigned short* a_ = gA + (kt) * 32;                                    \
    async_cp16(a_, d_);                                                           \
    async_cp16(a_ + (size_t)64  * CDIM, d_ + 2048);                               \
    async_cp16(a_ + (size_t)128 * CDIM, d_ + 4096);                               \
    async_cp16(a_ + (size_t)192 * CDIM, d_ + 6144);                               \
    const unsigned short* b_ = gB + (kt) * 32;                                    \
    async_cp16(b_, d_ + 8192);                                                    \
    async_cp16(b_ + (size_t)64 * CDIM, d_ + 10240); }

  f32x4 acc[8][4] = {};

  // prologue: stage tiles 0,1 ; ensure tile 0 landed (tile 1's 6 in flight)
  STAGE(0, 0); STAGE(1, 1);
  asm volatile("s_waitcnt vmcnt(6)" ::: "memory");
  __builtin_amdgcn_s_barrier();

  for (int kt = 0; kt < 24; ++kt) {
    const int s = kt % 3;
    const unsigned short* bp = ldsb + s * 12288;
    if (kt < 22) STAGE(kt + 2, (kt + 2) % 3);
    short8 af[8], bf[4];
#pragma unroll
    for (int i = 0; i < 8; ++i) af[i] = *(const short8*)(bp + (wm + i * 16 + lr) * 32 + kch);
#pragma unroll
    for (int j = 0; j < 4; ++j) bf[j] = *(const short8*)(bp + 8192 + (wn + j * 16 + lr) * 32 + kch);
    __builtin_amdgcn_s_setprio(1);
#pragma unroll
    for (int i = 0; i < 8; ++i)
#pragma unroll
      for (int j = 0; j < 4; ++j)
        acc[i][j] = __builtin_amdgcn_mfma_f32_16x16x32_bf16(af[i], bf[j], acc[i][j], 0, 0, 0);
    __builtin_amdgcn_s_setprio(0);
    if (kt < 22)       { asm volatile("s_waitcnt vmcnt(6)" ::: "memory"); }  // kt+1 landed
    else if (kt == 22) { asm volatile("s_waitcnt vmcnt(0)" ::: "memory"); }  // tail drain
    __builtin_amdgcn_s_barrier();
  }
#undef STAGE

  // epilogue; M-tail guard: whole-wave skip when rows OOB (mt==24, wm==128)
  if (mrow0 + wm < BN_TOT) {
#pragma unroll
    for (int i = 0; i < 8; ++i)
#pragma unroll
      for (int j = 0; j < 4; ++j) {
        const int gr = mrow0 + wm + i * 16 + lq * 4;   // C/D: row=(lane>>4)*4+reg, col=lane&15
        const int gc = colBase + wn + j * 16 + lr;
        unsigned short* cp = C + (size_t)gr * CDIM + gc;
#pragma unroll
        for (int r = 0; r < 4; ++r)
          cp[(size_t)r * CDIM] = f2bf(acc[i][j][r]);
      }
  }
}

// ---------- fully fused routing loop (R0 exact) ----------
__global__ __launch_bounds__(192) void k_iter3(const unsigned short* __restrict__ xw1b,
                                               const unsigned short* __restrict__ cw1,
                                               const unsigned short* __restrict__ pw1b,
                                               const unsigned short* __restrict__ projb,
                                               const float* __restrict__ b1,
                                               const float* __restrict__ w2,
                                               float* __restrict__ outc,
                                               float* __restrict__ outr) {
  __shared__ float red[3][NVIEW];
  __shared__ float aa[NVIEW];
  const int bn = blockIdx.x, t = threadIdx.x, wid = t >> 6, lane = t & 63;
  const int h = t * 4;
  const float4 bv = *(const float4*)(b1 + h);
  const float4 wv = *(const float4*)(w2 + h);
  float cw[4];
  { uint2 c = *(const uint2*)(cw1 + (size_t)bn * CDIM + h);
    cw[0] = bf_lo(c.x); cw[1] = bf_hi(c.x); cw[2] = bf_lo(c.y); cw[3] = bf_hi(c.y); }
  float xw[NVIEW][4], pf[NVIEW][4];
#pragma unroll
  for (int v = 0; v < NVIEW; ++v) {
    uint2 q = *(const uint2*)(xw1b + ((size_t)v * BN_TOT + bn) * CDIM + h);
    xw[v][0] = bf_lo(q.x) + bv.x; xw[v][1] = bf_hi(q.x) + bv.y;
    xw[v][2] = bf_lo(q.y) + bv.z; xw[v][3] = bf_hi(q.y) + bv.w;
    uint2 p = *(const uint2*)(pw1b + ((size_t)v * BN_TOT + bn) * CDIM + h);
    pf[v][0] = bf_lo(p.x); pf[v][1] = bf_hi(p.x);
    pf[v][2] = bf_lo(p.y); pf[v][3] = bf_hi(p.y);
  }
  for (int it = 0; it < 3; ++it) {
    float part[NVIEW];
#pragma unroll
    for (int v = 0; v < NVIEW; ++v) {
      float p;
      p = wv.x * ftanh(xw[v][0] + cw[0]);
      p = fmaf(wv.y, ftanh(xw[v][1] + cw[1]), p);
      p = fmaf(wv.z, ftanh(xw[v][2] + cw[2]), p);
      p = fmaf(wv.w, ftanh(xw[v][3] + cw[3]), p);
      part[v] = p;
    }
#pragma unroll
    for (int off = 32; off > 0; off >>= 1)
#pragma unroll
      for (int v = 0; v < NVIEW; ++v) part[v] += __shfl_down(part[v], off);
    if (lane == 0)
#pragma unroll
      for (int v = 0; v < NVIEW; ++v) red[wid][v] = part[v];
    __syncthreads();
    if (t == 0) {
      float s[NVIEW];
#pragma unroll
      for (int v = 0; v < NVIEW; ++v) s[v] = red[0][v] + red[1][v] + red[2][v];
      float m = s[0];
#pragma unroll
      for (int v = 1; v < NVIEW; ++v) m = fmaxf(m, s[v]);
      float a[NVIEW], sum = 0.f;
#pragma unroll
      for (int v = 0; v < NVIEW; ++v) { a[v] = __expf(s[v] - m); sum += a[v]; }
      const float inv = 1.f / sum;
#pragma unroll
      for (int v = 0; v < NVIEW; ++v) { a[v] *= inv; aa[v] = a[v]; }
      if (it == 2) {
        float ent = 0.f;
#pragma unroll
        for (int v = 0; v < NVIEW; ++v) ent -= a[v] * logf(a[v] + 1e-8f);
        outr[bn] = 1.f - ent * 0.6213349345596119f;  // 1/ln(5)
      }
    }
    __syncthreads();
    if (it < 2) {
      float n0 = 0, n1 = 0, n2 = 0, n3 = 0;
#pragma unroll
      for (int v = 0; v < NVIEW; ++v) {
        const float av = aa[v];
        n0 = fmaf(av, pf[v][0], n0); n1 = fmaf(av, pf[v][1], n1);
        n2 = fmaf(av, pf[v][2], n2); n3 = fmaf(av, pf[v][3], n3);
      }
      cw[0] = n0; cw[1] = n1; cw[2] = n2; cw[3] = n3;
    } else {
      float r0 = 0, r1 = 0, r2 = 0, r3 = 0;
#pragma unroll
      for (int v = 0; v < NVIEW; ++v) {
        const float av = aa[v];
        uint2 p = *(const uint2*)(projb + ((size_t)v * BN_TOT + bn) * CDIM + h);
        r0 = fmaf(av, bf_lo(p.x), r0); r1 = fmaf(av, bf_hi(p.x), r1);
        r2 = fmaf(av, bf_lo(p.y), r2); r3 = fmaf(av, bf_hi(p.y), r3);
      }
      float4 of; of.x = r0; of.y = r1; of.z = r2; of.w = r3;
      *(float4*)(outc + (size_t)bn * CDIM + h) = of;
    }
  }
}

extern "C" void kernel_launch(void* const* d_in, const int* in_sizes, int n_in,
                              void* d_out, int out_size, void* d_ws, size_t ws_size,
                              hipStream_t stream) {
  (void)in_sizes; (void)n_in; (void)out_size; (void)ws_size;
  const float* x  = (const float*)d_in[0];   // [B,V,N,C] fp32
  const float* wv = (const float*)d_in[1];   // [V,C,C]
  const float* w1 = (const float*)d_in[2];   // [2C,H]
  const float* b1 = (const float*)d_in[3];   // [H]
  const float* w2 = (const float*)d_in[4];   // [H,1]
  // d_in[5] = b2: uniform shift over views -> softmax-invariant, unused.

  // workspace: 86,016,000 ushorts = 172 MB (R0's exact known-safe layout)
  unsigned short* ws   = (unsigned short*)d_ws;
  unsigned short* wvT  = ws;                             //  2,949,120  [V][d][c]
  unsigned short* w1aT = ws + 2949120;                   //    589,824
  unsigned short* w1bT = ws + 3538944;                   //    589,824
  unsigned short* xb   = ws + 4128768;                   // 24,084,480  [V,BN,C]; dead after GEMM A
  unsigned short* pw1b = ws + 4128768;                   //   (aliased onto xb)
  unsigned short* projb= ws + 28213248;                  // 24,084,480
  unsigned short* xw1b = ws + 52297728;                  // 24,084,480
  unsigned short* cb   = ws + 76382208;                  //  4,816,896
  unsigned short* cw1  = ws + 81199104;                  //  4,816,896  (end: 86,016,000)

  float* outc = (float*)d_out;                           // c [B,N,C] fp32
  float* outr = outc + SLAB;                             // r [B,N]   fp32

  // 1: transposes + xb/mean in ONE launch (R4-verified merged structure)
  k_tr2<<<dim3(24, 24, 8), dim3(32, 8), 0, stream>>>(wv, w1, x, wvT, w1aT, w1bT, xb, cb);
  // 2: GEMM A: proj_v = xb_v @ wv_v ; xw1_v = xb_v @ w1a ; cw1 = cb @ w1b
  gemm_w<0><<<1650, 256, 73728, stream>>>(xb, cb, wvT, w1aT, w1bT, projb, xw1b, cw1);
  // 3: GEMM B: pw1b_v = proj_v @ w1b (writes over dead xb)
  gemm_w<1><<<750, 256, 73728, stream>>>(projb, nullptr, nullptr, nullptr, w1bT,
                                         pw1b, nullptr, nullptr);
  // 4: fused routing: 3 iterations pointwise in (b,n)
  k_iter3<<<BN_TOT, 192, 0, stream>>>(xw1b, cw1, pw1b, projb, b1, w2, outc, outr);
}